// Round 17
// baseline (83.447 us; speedup 1.0000x reference)
//
#include <hip/hip_runtime.h>
#include <math.h>

// Problem constants (batch=1024, dim_z=32, n_samples=32, agg_size=256)
#define B    1024
#define D    32
#define NS   32
#define AGG  256
#define NC   4
#define M    8192            // samples per chunk
#define NEV  1024            // eval blocks (262144 threads x 4 terms = 1M terms)

// Table: L(z)=log2 S(z) on z in [-32,32], h=1/16, 1024 nodes/(c,k)  (absmax 0.0 at this h)
#define TN     1024
#define ZMIN   (-32.0f)
#define INVH   16.0f
#define HH     0.0625f
#define ZCLAMP 31.9f

// ws: [0] counter | @256 partial[1024] 4KB | @8192 params 512KB
//     | @532480 msd 256KB | @794624 table 1MB
#define WS_PARTIAL 256
#define WS_PARAMS  8192
#define WS_MSD     532480
#define WS_TABLE   794624
#define WS_NEED    (794624 + 128 * TN * 8)

#define LOG2E 1.4426950408889634f
#define LN2   0.6931471805599453f

// params[(ck<<8)|i] = {A,B,C,0}: arg(z)=A z^2+B z+C (log2 units)
// msd[row*D+k] = {mu, sd}
__global__ __launch_bounds__(256) void ksetup(const float* __restrict__ mean,
                                              const float* __restrict__ logvar,
                                              float4* __restrict__ params,
                                              float2* __restrict__ msd,
                                              unsigned* __restrict__ counter)
{
    const int tid = blockIdx.x * 256 + threadIdx.x;   // over B*D, k fastest
    if (tid == 0) counter[0] = 0u;
    const int row = tid >> 5;
    const int k   = tid & (D - 1);
    const int c   = row >> 8;
    const int i   = row & (AGG - 1);
    const float mu = mean[tid];
    const float lv = logvar[tid];
    const float ev = __builtin_amdgcn_exp2f(-lv * LOG2E);   // exp(-lv); lv~N(0,1): safe
    params[(((c << 5) | k) << 8) | i] =
        make_float4(-0.5f * LOG2E * ev,
                    LOG2E * mu * ev,
                    -0.5f * LOG2E * fmaf(mu * mu, ev, lv), 0.f);
    msd[tid] = make_float2(mu, __builtin_amdgcn_exp2f(0.5f * LOG2E * lv));
}

// ktable: r16 VERBATIM.
__global__ __launch_bounds__(256) void ktable(const float4* __restrict__ params,
                                              float2* __restrict__ table)
{
    const int bid  = blockIdx.x;
    const int ck   = bid >> 4;
    const int g0   = (bid & 15) << 6;
    const int t    = threadIdx.x;
    const int lane = t & 63;
    const int wv   = t >> 6;

    __shared__ float4 ps[AGG];
    ps[t] = params[(ck << 8) | t];
    __syncthreads();

    const float z = fmaf((float)(g0 + lane), HH, ZMIN);
    float acc = 0.f, dacc = 0.f;
#pragma unroll 16
    for (int i = 0; i < 64; ++i) {
        const float4 p = ps[(wv << 6) + i];
        const float ap = fmaf(p.x, z, p.y);
        const float w  = __builtin_amdgcn_exp2f(fmaf(ap, z, p.z));
        acc += w;
        dacc = fmaf(w, fmaf(2.f, ap, -p.y), dacc);
    }
    __shared__ float2 part[256];
    part[t] = make_float2(acc, dacc);
    __syncthreads();
    if (t < 64) {
        const float2 p0 = part[t];
        const float2 p1 = part[t + 64];
        const float2 p2 = part[t + 128];
        const float2 p3 = part[t + 192];
        const float a  = (p0.x + p1.x) + (p2.x + p3.x);
        const float d  = (p0.y + p1.y) + (p2.y + p3.y);
        const float ag = fmaxf(a, 1e-30f);
        table[(ck << 10) | (g0 + t)] =
            make_float2(__builtin_amdgcn_logf(ag),
                        d * __builtin_amdgcn_rcpf(ag) * HH);
    }
}

// keval: r16 VERBATIM (launched 3x this round as an ablation probe; idempotent:
// the counter passes NBLK-1 only once per kernel_launch, so out is written once).
__global__ __launch_bounds__(256) void keval(const float* __restrict__ eps,
                                             const float2* __restrict__ msd,
                                             const float2* __restrict__ table,
                                             float* __restrict__ partial,
                                             unsigned* __restrict__ counter,
                                             float* __restrict__ out)
{
    const int t    = threadIdx.x;
    const int gidx = (blockIdx.x * 256 + t) << 2;     // flat (c,j,k), k fastest
    const int c    = gidx >> 18;                      // 8192*32 = 2^18 per chunk
    const int r18  = gidx & 262143;
    const int j    = r18 >> 5;
    const int k0   = r18 & 31;                        // multiple of 4
    const int row  = (c << 8) + (j >> 5);

    const float4 e4  = *(const float4*)(eps + gidx);                      // 16B coalesced
    const float* mp  = (const float*)(msd + ((row << 5) + k0));
    const float4 m01 = *(const float4*)(mp);                              // {mu0,sd0,mu1,sd1}
    const float4 m23 = *(const float4*)(mp + 4);                          // {mu2,sd2,mu3,sd3}

    const int ckb = (c << 5) + k0;

    float r = 0.f;
    {
        const float e[4]  = {e4.x, e4.y, e4.z, e4.w};
        const float mu[4] = {m01.x, m01.z, m23.x, m23.z};
        const float sd[4] = {m01.y, m01.w, m23.y, m23.w};
#pragma unroll
        for (int kk = 0; kk < 4; ++kk) {
            const float z  = fmaf(e[kk], sd[kk], mu[kk]);
            const float zc = fminf(fmaxf(z, -ZCLAMP), ZCLAMP);
            const float x  = fmaf(zc, INVH, 512.0f);      // (zc-ZMIN)*INVH
            const float fg = floorf(x);
            const float f  = x - fg;
            const int  ig  = (int)fg;                     // in [1,1022]
            const float2* __restrict__ tg = table + ((ckb + kk) << 10);
            const float2 n0 = tg[ig];
            const float2 n1 = tg[ig + 1];
            const float dl  = n1.x - n0.x;
            const float c2  = 3.f * dl - 2.f * n0.y - n1.y;
            const float c3  = n0.y + n1.y - 2.f * dl;
            const float L   = fmaf(f, fmaf(f, fmaf(f, c3, c2), n0.y), n0.x);
            r += fmaf(LN2, L, 0.5f * z * z);
        }
    }

    // deterministic block reduction
    for (int off = 32; off > 0; off >>= 1) r += __shfl_down(r, off, 64);
    __shared__ float wsum[4];
    if ((t & 63) == 0) wsum[t >> 6] = r;
    __syncthreads();

    __shared__ int isLast;
    if (t == 0) {
        partial[blockIdx.x] = (wsum[0] + wsum[1]) + (wsum[2] + wsum[3]);
        __threadfence();
        const unsigned old = atomicAdd(counter, 1u);
        isLast = (old == (unsigned)(NEV - 1));
    }
    __syncthreads();
    if (isLast) {
        __threadfence();
        double s = 0.0;
#pragma unroll
        for (int i = 0; i < NEV / 256; ++i) s += (double)partial[i * 256 + t];
        __shared__ double sd2[256];
        sd2[t] = s;
        __syncthreads();
        for (int off = 128; off > 0; off >>= 1) {
            if (t < off) sd2[t] += sd2[t + off];
            __syncthreads();
        }
        if (t == 0)
            out[0] = (float)(sd2[0] * (1.0 / (double)(NC * M))
                             - (double)D * 5.545177444479562);   // - D*ln(256)
    }
}

// ---- fallback (ws too small; not expected) ----
__global__ void kzero(unsigned* __restrict__ counter) { counter[0] = 0u; }

__global__ __launch_bounds__(256) void kfb(const float* __restrict__ eps,
                                           const float* __restrict__ mean,
                                           const float* __restrict__ logvar,
                                           float* __restrict__ partial,
                                           unsigned* __restrict__ counter,
                                           float* __restrict__ out)
{
    const int bid = blockIdx.x;
    const int ck  = bid >> 3;
    const int q   = bid & 7;
    const int c   = ck >> 5;
    const int k   = ck & (D - 1);
    const int j0  = q << 10;
    const int t   = threadIdx.x;

    __shared__ float4 prm[AGG];
    {
        const int row  = (c << 8) + t;
        const float mu = mean[row * D + k];
        const float lv = logvar[row * D + k];
        const float ev = __builtin_amdgcn_exp2f(-lv * LOG2E);
        prm[t] = make_float4(-0.5f * LOG2E * ev, LOG2E * mu * ev,
                             -0.5f * LOG2E * fmaf(mu * mu, ev, lv),
                             __builtin_amdgcn_exp2f(0.5f * LOG2E * lv));
    }
    __syncthreads();

    float zv[4], acc[4];
#pragma unroll
    for (int u = 0; u < 4; ++u) {
        const int j    = j0 + t + (u << 8);
        const float4 p = prm[j >> 5];
        const float mu = -0.5f * p.y * __builtin_amdgcn_rcpf(p.x);
        zv[u]  = fmaf(eps[(size_t)((c << 13) + j) * D + k], p.w, mu);
        acc[u] = 0.f;
    }
#pragma unroll 4
    for (int i = 0; i < AGG; ++i) {
        const float4 p = prm[i];
#pragma unroll
        for (int u = 0; u < 4; ++u)
            acc[u] += __builtin_amdgcn_exp2f(fmaf(fmaf(p.x, zv[u], p.y), zv[u], p.z));
    }
    float r = 0.f;
#pragma unroll
    for (int u = 0; u < 4; ++u)
        r += LN2 * __builtin_amdgcn_logf(acc[u]) + 0.5f * zv[u] * zv[u];

    for (int off = 32; off > 0; off >>= 1) r += __shfl_down(r, off, 64);
    __shared__ float wsum[4];
    if ((t & 63) == 0) wsum[t >> 6] = r;
    __syncthreads();
    __shared__ int isLast;
    if (t == 0) {
        partial[bid] = (wsum[0] + wsum[1]) + (wsum[2] + wsum[3]);
        __threadfence();
        const unsigned old = atomicAdd(counter, 1u);
        isLast = (old == (unsigned)(NEV - 1));
    }
    __syncthreads();
    if (isLast) {
        __threadfence();
        double s = 0.0;
#pragma unroll
        for (int i = 0; i < NEV / 256; ++i) s += (double)partial[i * 256 + t];
        __shared__ double sd2[256];
        sd2[t] = s;
        __syncthreads();
        for (int off = 128; off > 0; off >>= 1) {
            if (t < off) sd2[t] += sd2[t + off];
            __syncthreads();
        }
        if (t == 0)
            out[0] = (float)(sd2[0] * (1.0 / (double)(NC * M))
                             - (double)D * 5.545177444479562);
    }
}

extern "C" void kernel_launch(void* const* d_in, const int* in_sizes, int n_in,
                              void* d_out, int out_size, void* d_ws, size_t ws_size,
                              hipStream_t stream)
{
    const float* mean   = (const float*)d_in[0];
    const float* logvar = (const float*)d_in[1];
    const float* eps    = (const float*)d_in[2];
    float* out = (float*)d_out;

    unsigned* counter = (unsigned*)d_ws;
    float*    partial = (float*)((char*)d_ws + WS_PARTIAL);
    float4*   params  = (float4*)((char*)d_ws + WS_PARAMS);
    float2*   msd     = (float2*)((char*)d_ws + WS_MSD);
    float2*   table   = (float2*)((char*)d_ws + WS_TABLE);

    if (ws_size >= (size_t)WS_NEED) {
        ksetup<<<(B * D) / 256, 256, 0, stream>>>(mean, logvar, params, msd, counter);
        ktable<<<128 * 16, 256, 0, stream>>>(params, table);
        // ABLATION PROBE: keval x3 (idempotent). keval_dur = (r17_total - r16_total)/2.
        keval<<<NEV, 256, 0, stream>>>(eps, msd, table, partial, counter, out);
        keval<<<NEV, 256, 0, stream>>>(eps, msd, table, partial, counter, out);
        keval<<<NEV, 256, 0, stream>>>(eps, msd, table, partial, counter, out);
    } else {
        kzero<<<1, 64, 0, stream>>>(counter);
        kfb<<<NEV, 256, 0, stream>>>(eps, mean, logvar, partial, counter, out);
    }
}

// Round 18
// 30.184 us; speedup vs baseline: 2.7646x; 2.7646x over previous
//
#include <hip/hip_runtime.h>
#include <math.h>

// Problem constants (batch=1024, dim_z=32, n_samples=32, agg_size=256)
#define B    1024
#define D    32
#define AGG  256
#define NC   4
#define M    8192            // samples per chunk
#define NEV  1024            // eval blocks: 128 ck x 8 segments of 1024 samples

// Table: L(z)=log2 S(z) on z in [-32,32], h=1/16, 1024 nodes/(c,k) (absmax 0.0 at this h)
#define TN     1024
#define ZMIN   (-32.0f)
#define INVH   16.0f
#define HH     0.0625f
#define ZCLAMP 31.9f

// ws: @0 partial[1024] 4KB | @8192 params 512KB | @532480 msdT 256KB
//     | @794624 table 1MB | @1843200 epsT 4MB
#define WS_PARAMS  8192
#define WS_MSDT    532480
#define WS_TABLE   794624
#define WS_EPST    1843200
#define WS_NEED    6037504

#define LOG2E 1.4426950408889634f
#define LN2   0.6931471805599453f

// params[(ck<<8)|i] = {A,B,C,0}: arg(z)=A z^2+B z+C (log2 units)
// msdT[(ck<<8)|i]  = {mu, sd}   (ck-major so keval reads it coalesced)
__global__ __launch_bounds__(256) void ksetup(const float* __restrict__ mean,
                                              const float* __restrict__ logvar,
                                              float4* __restrict__ params,
                                              float2* __restrict__ msdT)
{
    const int tid = blockIdx.x * 256 + threadIdx.x;   // over B*D, k fastest
    const int row = tid >> 5;
    const int k   = tid & (D - 1);
    const int c   = row >> 8;
    const int i   = row & (AGG - 1);
    const int ck  = (c << 5) | k;
    const float mu = mean[tid];
    const float lv = logvar[tid];
    const float ev = __builtin_amdgcn_exp2f(-lv * LOG2E);   // exp(-lv); lv~N(0,1): safe
    params[(ck << 8) | i] =
        make_float4(-0.5f * LOG2E * ev,
                    LOG2E * mu * ev,
                    -0.5f * LOG2E * fmaf(mu * mu, ev, lv), 0.f);
    msdT[(ck << 8) | i] = make_float2(mu, __builtin_amdgcn_exp2f(0.5f * LOG2E * lv));
}

// Transpose eps[c][j][k] -> epsT[ck][j] via 32x33 LDS tile; both sides coalesced.
__global__ __launch_bounds__(256) void ktrans(const float* __restrict__ eps,
                                              float* __restrict__ epsT)
{
    const int bid = blockIdx.x;            // 4 * 256 blocks
    const int c   = bid >> 8;
    const int j0t = (bid & 255) << 5;
    const int t   = threadIdx.x;
    const int x   = t & 31;
    const int y0  = t >> 5;
    __shared__ float tile[32][33];
#pragma unroll
    for (int p = 0; p < 4; ++p) {
        const int r = (p << 3) + y0;
        tile[r][x] = eps[((size_t)c * M + j0t + r) * D + x];
    }
    __syncthreads();
#pragma unroll
    for (int p = 0; p < 4; ++p) {
        const int kk = (p << 3) + y0;
        epsT[(((size_t)c * D + kk) << 13) + j0t + x] = tile[x][kk];
    }
}

// ktable: r16 VERBATIM (control; ~17us by ledger — attacked next round).
__global__ __launch_bounds__(256) void ktable(const float4* __restrict__ params,
                                              float2* __restrict__ table)
{
    const int bid  = blockIdx.x;
    const int ck   = bid >> 4;
    const int g0   = (bid & 15) << 6;
    const int t    = threadIdx.x;
    const int lane = t & 63;
    const int wv   = t >> 6;

    __shared__ float4 ps[AGG];
    ps[t] = params[(ck << 8) | t];
    __syncthreads();

    const float z = fmaf((float)(g0 + lane), HH, ZMIN);
    float acc = 0.f, dacc = 0.f;
#pragma unroll 16
    for (int i = 0; i < 64; ++i) {
        const float4 p = ps[(wv << 6) + i];
        const float ap = fmaf(p.x, z, p.y);
        const float w  = __builtin_amdgcn_exp2f(fmaf(ap, z, p.z));
        acc += w;
        dacc = fmaf(w, fmaf(2.f, ap, -p.y), dacc);
    }
    __shared__ float2 part[256];
    part[t] = make_float2(acc, dacc);
    __syncthreads();
    if (t < 64) {
        const float2 p0 = part[t];
        const float2 p1 = part[t + 64];
        const float2 p2 = part[t + 128];
        const float2 p3 = part[t + 192];
        const float a  = (p0.x + p1.x) + (p2.x + p3.x);
        const float d  = (p0.y + p1.y) + (p2.y + p3.y);
        const float ag = fmaxf(a, 1e-30f);
        table[(ck << 10) | (g0 + t)] =
            make_float2(__builtin_amdgcn_logf(ag),
                        d * __builtin_amdgcn_rcpf(ag) * HH);
    }
}

// keval: per-(ck,q) block, LDS table, coalesced epsT/msdT.
// NO __threadfence, NO atomic counter — plain partial store (fence-storm fix).
__global__ __launch_bounds__(256) void keval(const float* __restrict__ epsT,
                                             const float2* __restrict__ msdT,
                                             const float2* __restrict__ table,
                                             float* __restrict__ partial)
{
    const int bid = blockIdx.x;
    const int ck  = bid >> 3;
    const int q   = bid & 7;
    const int j0  = q << 10;
    const int t   = threadIdx.x;

    // coalesced: thread t owns samples j0+4t..4t+3 (one 16B load)
    const float4 e4 = *(const float4*)(epsT + ((size_t)ck << 13) + j0 + (t << 2));
    const float e[4] = {e4.x, e4.y, e4.z, e4.w};

    __shared__ float2 rowp[32];
    if (t < 32) rowp[t] = msdT[(ck << 8) + (q << 5) + t];   // 256B coalesced

    __shared__ float2 tab[TN];
    const float2* __restrict__ gt = table + (ck << 10);
#pragma unroll
    for (int p = 0; p < 4; ++p)
        tab[t + (p << 8)] = gt[t + (p << 8)];
    __syncthreads();

    const float2 ms = rowp[t >> 3];           // 4 samples share one row
    float r = 0.f;
#pragma unroll
    for (int u = 0; u < 4; ++u) {
        const float z  = fmaf(e[u], ms.y, ms.x);
        const float zc = fminf(fmaxf(z, -ZCLAMP), ZCLAMP);
        const float x  = fmaf(zc, INVH, 512.0f);      // (zc-ZMIN)*INVH
        const float fg = floorf(x);
        const float f  = x - fg;
        const int  ig  = (int)fg;                     // in [1,1022]
        const float2 n0 = tab[ig];
        const float2 n1 = tab[ig + 1];
        const float dl  = n1.x - n0.x;
        const float c2  = 3.f * dl - 2.f * n0.y - n1.y;
        const float c3  = n0.y + n1.y - 2.f * dl;
        const float L   = fmaf(f, fmaf(f, fmaf(f, c3, c2), n0.y), n0.x);
        r += fmaf(LN2, L, 0.5f * z * z);
    }

    for (int off = 32; off > 0; off >>= 1) r += __shfl_down(r, off, 64);
    __shared__ float wsum[4];
    if ((t & 63) == 0) wsum[t >> 6] = r;
    __syncthreads();
    if (t == 0) partial[bid] = (wsum[0] + wsum[1]) + (wsum[2] + wsum[3]);
}

// Separate 1-block finish (kernel boundary = coherence; no fences anywhere).
__global__ __launch_bounds__(256) void kfinal(const float* __restrict__ partial,
                                              float* __restrict__ out)
{
    const int t = threadIdx.x;
    double s = 0.0;
#pragma unroll
    for (int i = 0; i < NEV / 256; ++i) s += (double)partial[i * 256 + t];
    __shared__ double sd[256];
    sd[t] = s;
    __syncthreads();
    for (int off = 128; off > 0; off >>= 1) {
        if (t < off) sd[t] += sd[t + off];
        __syncthreads();
    }
    if (t == 0)
        out[0] = (float)(sd[0] * (1.0 / (double)(NC * M))
                         - (double)D * 5.545177444479562);   // - D*ln(256)
}

// ---- fallback (ws too small; not expected: ws is ~256MB) ----
__global__ __launch_bounds__(256) void kfb(const float* __restrict__ eps,
                                           const float* __restrict__ mean,
                                           const float* __restrict__ logvar,
                                           float* __restrict__ partial)
{
    const int bid = blockIdx.x;
    const int ck  = bid >> 3;
    const int q   = bid & 7;
    const int c   = ck >> 5;
    const int k   = ck & (D - 1);
    const int j0  = q << 10;
    const int t   = threadIdx.x;

    __shared__ float4 prm[AGG];
    {
        const int row  = (c << 8) + t;
        const float mu = mean[row * D + k];
        const float lv = logvar[row * D + k];
        const float ev = __builtin_amdgcn_exp2f(-lv * LOG2E);
        prm[t] = make_float4(-0.5f * LOG2E * ev, LOG2E * mu * ev,
                             -0.5f * LOG2E * fmaf(mu * mu, ev, lv),
                             __builtin_amdgcn_exp2f(0.5f * LOG2E * lv));
    }
    __syncthreads();

    float zv[4], acc[4];
#pragma unroll
    for (int u = 0; u < 4; ++u) {
        const int j    = j0 + t + (u << 8);
        const float4 p = prm[j >> 5];
        const float mu = -0.5f * p.y * __builtin_amdgcn_rcpf(p.x);
        zv[u]  = fmaf(eps[(size_t)((c << 13) + j) * D + k], p.w, mu);
        acc[u] = 0.f;
    }
#pragma unroll 4
    for (int i = 0; i < AGG; ++i) {
        const float4 p = prm[i];
#pragma unroll
        for (int u = 0; u < 4; ++u)
            acc[u] += __builtin_amdgcn_exp2f(fmaf(fmaf(p.x, zv[u], p.y), zv[u], p.z));
    }
    float r = 0.f;
#pragma unroll
    for (int u = 0; u < 4; ++u)
        r += LN2 * __builtin_amdgcn_logf(acc[u]) + 0.5f * zv[u] * zv[u];

    for (int off = 32; off > 0; off >>= 1) r += __shfl_down(r, off, 64);
    __shared__ float wsum[4];
    if ((t & 63) == 0) wsum[t >> 6] = r;
    __syncthreads();
    if (t == 0) partial[bid] = (wsum[0] + wsum[1]) + (wsum[2] + wsum[3]);
}

extern "C" void kernel_launch(void* const* d_in, const int* in_sizes, int n_in,
                              void* d_out, int out_size, void* d_ws, size_t ws_size,
                              hipStream_t stream)
{
    const float* mean   = (const float*)d_in[0];
    const float* logvar = (const float*)d_in[1];
    const float* eps    = (const float*)d_in[2];
    float* out = (float*)d_out;

    float*  partial = (float*)d_ws;
    float4* params  = (float4*)((char*)d_ws + WS_PARAMS);
    float2* msdT    = (float2*)((char*)d_ws + WS_MSDT);
    float2* table   = (float2*)((char*)d_ws + WS_TABLE);
    float*  epsT    = (float*)((char*)d_ws + WS_EPST);

    if (ws_size >= (size_t)WS_NEED) {
        ksetup<<<(B * D) / 256, 256, 0, stream>>>(mean, logvar, params, msdT);
        ktrans<<<NC * 256, 256, 0, stream>>>(eps, epsT);
        ktable<<<128 * 16, 256, 0, stream>>>(params, table);
        keval<<<NEV, 256, 0, stream>>>(epsT, msdT, table, partial);
    } else {
        kfb<<<NEV, 256, 0, stream>>>(eps, mean, logvar, partial);
    }
    kfinal<<<1, 256, 0, stream>>>(partial, out);
}

// Round 19
// 22.459 us; speedup vs baseline: 3.7155x; 1.3440x over previous
//
#include <hip/hip_runtime.h>
#include <math.h>

// Problem constants (batch=1024, dim_z=32, n_samples=32, agg_size=256)
#define B    1024
#define D    32
#define AGG  256
#define NC   4
#define M    8192            // samples per chunk
#define NEV  1024            // eval blocks: 128 ck x 8 segments of 1024 samples

// Table: L(z)=log2 S(z) on z in [-32,32], h=1/16, 1024 float nodes/(c,k)
#define TN     1024
#define ZMIN   (-32.0f)
#define INVH   16.0f
#define HH     0.0625f
#define ZCLAMP 31.8f         // keeps Catmull-Rom stencil ig-1..ig+2 in [2,1022]

// ws: @0 partial[1024] 4KB | @8192 params 512KB | @532480 msdT 256KB
//     | @794624 table 512KB | @1318912 epsT 4MB
#define WS_PARAMS  8192
#define WS_MSDT    532480
#define WS_TABLE   794624
#define WS_EPST    1318912
#define WS_NEED    5513216

#define LOG2E 1.4426950408889634f
#define LN2   0.6931471805599453f

// kprep = fused ksetup + ktrans (1024 blocks).
// All blocks: transpose eps[c][j][k] -> epsT[ck][j] (32x33 LDS tile, coalesced).
// Blocks < 128 additionally build params/msdT (coalesced reads, scattered stores):
//   params[(ck<<8)|i] = {A, B, C, rho}: arg(z)=A z^2+B z+C (log2 units),
//   rho = 2^{2Ah^2} = exp2(A/128)  (A<0 -> rho<=1, never overflows)
//   msdT[(ck<<8)|i]  = {mu, sd}
__global__ __launch_bounds__(256) void kprep(const float* __restrict__ eps,
                                             const float* __restrict__ mean,
                                             const float* __restrict__ logvar,
                                             float* __restrict__ epsT,
                                             float4* __restrict__ params,
                                             float2* __restrict__ msdT)
{
    const int bid = blockIdx.x;
    const int t   = threadIdx.x;

    // ---- transpose part (all 1024 blocks) ----
    {
        const int c   = bid >> 8;
        const int j0t = (bid & 255) << 5;
        const int x   = t & 31;
        const int y0  = t >> 5;
        __shared__ float tile[32][33];
#pragma unroll
        for (int p = 0; p < 4; ++p) {
            const int r = (p << 3) + y0;
            tile[r][x] = eps[((size_t)c * M + j0t + r) * D + x];
        }
        __syncthreads();
#pragma unroll
        for (int p = 0; p < 4; ++p) {
            const int kk = (p << 3) + y0;
            epsT[(((size_t)c * D + kk) << 13) + j0t + x] = tile[x][kk];
        }
    }

    // ---- params part (blocks 0..127 cover B*D = 32768 elements) ----
    if (bid < 128) {
        const int tid = bid * 256 + t;            // over B*D, k fastest
        const int row = tid >> 5;
        const int k   = tid & (D - 1);
        const int c   = row >> 8;
        const int i   = row & (AGG - 1);
        const int ck  = (c << 5) | k;
        const float mu = mean[tid];
        const float lv = logvar[tid];
        const float ev = __builtin_amdgcn_exp2f(-lv * LOG2E);   // exp(-lv)
        const float A  = -0.5f * LOG2E * ev;
        params[(ck << 8) | i] =
            make_float4(A, LOG2E * mu * ev,
                        -0.5f * LOG2E * fmaf(mu * mu, ev, lv),
                        __builtin_amdgcn_exp2f(A * 0.0078125f));   // rho = 2^(A/128)
        msdT[(ck << 8) | i] = make_float2(mu, __builtin_amdgcn_exp2f(0.5f * LOG2E * lv));
    }
}

// ktable: 512 blocks = 128 ck x 4 segments of 256 nodes.
// Thread = 4 consecutive nodes x wave's 64-comp quarter.
// One ds_read_b128 feeds 4 nodes (LDS /4); nodes 1-3 via ratio recurrence
// w_{g+1} = w_g * r, r_{g+1} = r * rho  (exps /2: only w0 and r per comp).
// d clamp <=126 is anti-NaN only (0*inf); when w0>0, geometry bounds d<=~17.
__global__ __launch_bounds__(256) void ktable(const float4* __restrict__ params,
                                              float* __restrict__ table)
{
    const int bid  = blockIdx.x;
    const int ck   = bid >> 2;
    const int seg  = bid & 3;
    const int t    = threadIdx.x;
    const int lane = t & 63;
    const int wv   = t >> 6;

    __shared__ float4 ps[AGG];
    ps[t] = params[(ck << 8) | t];
    __syncthreads();

    const float z0 = fmaf((float)((seg << 8) + (lane << 2)), HH, ZMIN);
    const float tz = z0 + z0 + HH;                 // 2 z0 + h
    float a0 = 0.f, a1 = 0.f, a2 = 0.f, a3 = 0.f;
#pragma unroll 8
    for (int i = 0; i < 64; ++i) {
        const float4 p = ps[(wv << 6) + i];        // wave-uniform LDS broadcast
        const float ap = fmaf(p.x, z0, p.y);       // A z0 + B
        float w = __builtin_amdgcn_exp2f(fmaf(ap, z0, p.z));
        float d = HH * fmaf(p.x, tz, p.y);         // arg(z0+h)-arg(z0)
        d = fminf(d, 126.f);                       // anti-NaN (0 * inf) guard
        float r = __builtin_amdgcn_exp2f(d);
        a0 += w;
        w *= r; a1 += w; r *= p.w;
        w *= r; a2 += w; r *= p.w;
        w *= r; a3 += w;
    }

    __shared__ float part[4][256];                 // 4KB
    *(float4*)&part[wv][lane << 2] = make_float4(a0, a1, a2, a3);
    __syncthreads();
    const float s = ((part[0][t] + part[1][t]) + (part[2][t] + part[3][t]));
    table[(ck << 10) | (seg << 8) | t] =
        __builtin_amdgcn_logf(fmaxf(s, 1e-30f));
}

// keval: coalesced epsT float4, LDS float table (4KB), Catmull-Rom cubic
// (FD slopes from neighbors). No fences, no atomics — plain partial store.
__global__ __launch_bounds__(256) void keval(const float* __restrict__ epsT,
                                             const float2* __restrict__ msdT,
                                             const float* __restrict__ table,
                                             float* __restrict__ partial)
{
    const int bid = blockIdx.x;
    const int ck  = bid >> 3;
    const int q   = bid & 7;
    const int j0  = q << 10;
    const int t   = threadIdx.x;

    const float4 e4 = *(const float4*)(epsT + ((size_t)ck << 13) + j0 + (t << 2));
    const float e[4] = {e4.x, e4.y, e4.z, e4.w};

    __shared__ float2 rowp[32];
    if (t < 32) rowp[t] = msdT[(ck << 8) + (q << 5) + t];

    __shared__ float tab[TN];                      // 4KB
    const float* __restrict__ gt = table + (ck << 10);
#pragma unroll
    for (int p = 0; p < 4; ++p)
        tab[t + (p << 8)] = gt[t + (p << 8)];
    __syncthreads();

    const float2 ms = rowp[t >> 3];                // 4 samples share one row
    float r = 0.f;
#pragma unroll
    for (int u = 0; u < 4; ++u) {
        const float z  = fmaf(e[u], ms.y, ms.x);
        const float zc = fminf(fmaxf(z, -ZCLAMP), ZCLAMP);
        const float x  = fmaf(zc, INVH, 512.0f);   // (zc-ZMIN)*INVH
        const float fg = floorf(x);
        const float f  = x - fg;
        const int  ig  = (int)fg;                  // in [3,1020]
        const float Lm = tab[ig - 1];
        const float L0 = tab[ig];
        const float L1 = tab[ig + 1];
        const float L2 = tab[ig + 2];
        const float m0 = 0.5f * (L1 - Lm);
        const float m1 = 0.5f * (L2 - L0);
        const float dl = L1 - L0;
        const float c2 = 3.f * dl - 2.f * m0 - m1;
        const float c3 = m0 + m1 - 2.f * dl;
        const float L  = fmaf(f, fmaf(f, fmaf(f, c3, c2), m0), L0);
        r += fmaf(LN2, L, 0.5f * z * z);
    }

    for (int off = 32; off > 0; off >>= 1) r += __shfl_down(r, off, 64);
    __shared__ float wsum[4];
    if ((t & 63) == 0) wsum[t >> 6] = r;
    __syncthreads();
    if (t == 0) partial[bid] = (wsum[0] + wsum[1]) + (wsum[2] + wsum[3]);
}

// Separate 1-block finish (kernel boundary = coherence; no fences anywhere).
__global__ __launch_bounds__(256) void kfinal(const float* __restrict__ partial,
                                              float* __restrict__ out)
{
    const int t = threadIdx.x;
    double s = 0.0;
#pragma unroll
    for (int i = 0; i < NEV / 256; ++i) s += (double)partial[i * 256 + t];
    __shared__ double sd[256];
    sd[t] = s;
    __syncthreads();
    for (int off = 128; off > 0; off >>= 1) {
        if (t < off) sd[t] += sd[t + off];
        __syncthreads();
    }
    if (t == 0)
        out[0] = (float)(sd[0] * (1.0 / (double)(NC * M))
                         - (double)D * 5.545177444479562);   // - D*ln(256)
}

// ---- fallback (ws too small; not expected) ----
__global__ __launch_bounds__(256) void kfb(const float* __restrict__ eps,
                                           const float* __restrict__ mean,
                                           const float* __restrict__ logvar,
                                           float* __restrict__ partial)
{
    const int bid = blockIdx.x;
    const int ck  = bid >> 3;
    const int q   = bid & 7;
    const int c   = ck >> 5;
    const int k   = ck & (D - 1);
    const int j0  = q << 10;
    const int t   = threadIdx.x;

    __shared__ float4 prm[AGG];
    {
        const int row  = (c << 8) + t;
        const float mu = mean[row * D + k];
        const float lv = logvar[row * D + k];
        const float ev = __builtin_amdgcn_exp2f(-lv * LOG2E);
        prm[t] = make_float4(-0.5f * LOG2E * ev, LOG2E * mu * ev,
                             -0.5f * LOG2E * fmaf(mu * mu, ev, lv),
                             __builtin_amdgcn_exp2f(0.5f * LOG2E * lv));
    }
    __syncthreads();

    float zv[4], acc[4];
#pragma unroll
    for (int u = 0; u < 4; ++u) {
        const int j    = j0 + t + (u << 8);
        const float4 p = prm[j >> 5];
        const float mu = -0.5f * p.y * __builtin_amdgcn_rcpf(p.x);
        zv[u]  = fmaf(eps[(size_t)((c << 13) + j) * D + k], p.w, mu);
        acc[u] = 0.f;
    }
#pragma unroll 4
    for (int i = 0; i < AGG; ++i) {
        const float4 p = prm[i];
#pragma unroll
        for (int u = 0; u < 4; ++u)
            acc[u] += __builtin_amdgcn_exp2f(fmaf(fmaf(p.x, zv[u], p.y), zv[u], p.z));
    }
    float r = 0.f;
#pragma unroll
    for (int u = 0; u < 4; ++u)
        r += LN2 * __builtin_amdgcn_logf(acc[u]) + 0.5f * zv[u] * zv[u];

    for (int off = 32; off > 0; off >>= 1) r += __shfl_down(r, off, 64);
    __shared__ float wsum[4];
    if ((t & 63) == 0) wsum[t >> 6] = r;
    __syncthreads();
    if (t == 0) partial[bid] = (wsum[0] + wsum[1]) + (wsum[2] + wsum[3]);
}

extern "C" void kernel_launch(void* const* d_in, const int* in_sizes, int n_in,
                              void* d_out, int out_size, void* d_ws, size_t ws_size,
                              hipStream_t stream)
{
    const float* mean   = (const float*)d_in[0];
    const float* logvar = (const float*)d_in[1];
    const float* eps    = (const float*)d_in[2];
    float* out = (float*)d_out;

    float*  partial = (float*)d_ws;
    float4* params  = (float4*)((char*)d_ws + WS_PARAMS);
    float2* msdT    = (float2*)((char*)d_ws + WS_MSDT);
    float*  table   = (float*)((char*)d_ws + WS_TABLE);
    float*  epsT    = (float*)((char*)d_ws + WS_EPST);

    if (ws_size >= (size_t)WS_NEED) {
        kprep<<<NC * 256, 256, 0, stream>>>(eps, mean, logvar, epsT, params, msdT);
        ktable<<<128 * 4, 256, 0, stream>>>(params, table);
        keval<<<NEV, 256, 0, stream>>>(epsT, msdT, table, partial);
    } else {
        kfb<<<NEV, 256, 0, stream>>>(eps, mean, logvar, partial);
    }
    kfinal<<<1, 256, 0, stream>>>(partial, out);
}

// Round 20
// 21.341 us; speedup vs baseline: 3.9101x; 1.0524x over previous
//
#include <hip/hip_runtime.h>
#include <math.h>

// Problem constants (batch=1024, dim_z=32, n_samples=32, agg_size=256)
#define B    1024
#define D    32
#define AGG  256
#define NC   4
#define M    8192            // samples per chunk
#define NEV  1024            // eval blocks: 128 ck x 8 segments of 1024 samples

// Table: L(z)=log2 S(z) on z in [-32,32], h=1/16, 1024 float nodes/(c,k)
#define TN     1024
#define ZMIN   (-32.0f)
#define INVH   16.0f
#define HH     0.0625f
#define ZCLAMP 31.8f         // keeps Catmull-Rom stencil ig-1..ig+2 in [2,1022]

// ws: @0 partial[1024] 4KB | @8192 params 512KB | @532480 msdT 256KB
//     | @794624 table 512KB | @1318912 epsT 4MB
#define WS_PARAMS  8192
#define WS_MSDT    532480
#define WS_TABLE   794624
#define WS_EPST    1318912
#define WS_NEED    5513216

#define LOG2E 1.4426950408889634f
#define LN2   0.6931471805599453f

// kprep = fused ksetup + ktrans (1024 blocks), r19 VERBATIM.
__global__ __launch_bounds__(256) void kprep(const float* __restrict__ eps,
                                             const float* __restrict__ mean,
                                             const float* __restrict__ logvar,
                                             float* __restrict__ epsT,
                                             float4* __restrict__ params,
                                             float2* __restrict__ msdT)
{
    const int bid = blockIdx.x;
    const int t   = threadIdx.x;

    // ---- transpose part (all 1024 blocks) ----
    {
        const int c   = bid >> 8;
        const int j0t = (bid & 255) << 5;
        const int x   = t & 31;
        const int y0  = t >> 5;
        __shared__ float tile[32][33];
#pragma unroll
        for (int p = 0; p < 4; ++p) {
            const int r = (p << 3) + y0;
            tile[r][x] = eps[((size_t)c * M + j0t + r) * D + x];
        }
        __syncthreads();
#pragma unroll
        for (int p = 0; p < 4; ++p) {
            const int kk = (p << 3) + y0;
            epsT[(((size_t)c * D + kk) << 13) + j0t + x] = tile[x][kk];
        }
    }

    // ---- params part (blocks 0..127 cover B*D = 32768 elements) ----
    if (bid < 128) {
        const int tid = bid * 256 + t;            // over B*D, k fastest
        const int row = tid >> 5;
        const int k   = tid & (D - 1);
        const int c   = row >> 8;
        const int i   = row & (AGG - 1);
        const int ck  = (c << 5) | k;
        const float mu = mean[tid];
        const float lv = logvar[tid];
        const float ev = __builtin_amdgcn_exp2f(-lv * LOG2E);   // exp(-lv)
        const float A  = -0.5f * LOG2E * ev;
        params[(ck << 8) | i] =
            make_float4(A, LOG2E * mu * ev,
                        -0.5f * LOG2E * fmaf(mu * mu, ev, lv),
                        __builtin_amdgcn_exp2f(A * 0.0078125f));   // rho = 2^(A/128)
        msdT[(ck << 8) | i] = make_float2(mu, __builtin_amdgcn_exp2f(0.5f * LOG2E * lv));
    }
}

// ktable v3: 256 blocks x 1024 threads = 128 ck x 2 segments of 512 nodes.
// 16 waves/block, each wave owns a 16-comp group over the same 512 nodes;
// thread = 8 consecutive nodes. Per iter: 1 ds_read_b128 + 2 exps + ~25 VALU
// covers 8 nodes via the ratio recurrence w_{g+1}=w_g*r, r_{g+1}=r*rho.
// Totals vs r19: exps /2, ds_read /2, waves/SIMD 2 -> 4.
// d clamp <=126 is anti-NaN only (0*inf on fully-underflowed comps).
__global__ __launch_bounds__(1024) void ktable(const float4* __restrict__ params,
                                               float* __restrict__ table)
{
    const int bid  = blockIdx.x;
    const int ck   = bid >> 1;
    const int seg  = bid & 1;
    const int t    = threadIdx.x;
    const int lane = t & 63;
    const int wv   = t >> 6;                       // 16 comp groups

    __shared__ float4 ps[AGG];                     // 4KB
    if (t < AGG) ps[t] = params[(ck << 8) | t];
    __syncthreads();

    const int g0   = (seg << 9) + (lane << 3);     // node base for this thread
    const float z0 = fmaf((float)g0, HH, ZMIN);
    const float tz = z0 + z0 + HH;                 // 2 z0 + h
    float a0 = 0.f, a1 = 0.f, a2 = 0.f, a3 = 0.f;
    float a4 = 0.f, a5 = 0.f, a6 = 0.f, a7 = 0.f;
#pragma unroll
    for (int i = 0; i < 16; ++i) {
        const float4 p = ps[(wv << 4) + i];        // wave-uniform LDS broadcast
        const float ap = fmaf(p.x, z0, p.y);       // A z0 + B
        float w = __builtin_amdgcn_exp2f(fmaf(ap, z0, p.z));
        float d = HH * fmaf(p.x, tz, p.y);         // arg(z0+h)-arg(z0)
        d = fminf(d, 126.f);                       // anti-NaN (0 * inf) guard
        float r = __builtin_amdgcn_exp2f(d);
        a0 += w;
        w *= r; a1 += w; r *= p.w;
        w *= r; a2 += w; r *= p.w;
        w *= r; a3 += w; r *= p.w;
        w *= r; a4 += w; r *= p.w;
        w *= r; a5 += w; r *= p.w;
        w *= r; a6 += w; r *= p.w;
        w *= r; a7 += w;
    }

    __shared__ float part[16][512];                // 32KB
    {
        float* pb = &part[wv][lane << 3];
        *(float4*)pb       = make_float4(a0, a1, a2, a3);
        *(float4*)(pb + 4) = make_float4(a4, a5, a6, a7);
    }
    __syncthreads();
    if (t < 512) {
        float s = 0.f;
#pragma unroll
        for (int w = 0; w < 16; ++w) s += part[w][t];   // fixed order: deterministic
        table[(ck << 10) | (seg << 9) | t] =
            __builtin_amdgcn_logf(fmaxf(s, 1e-30f));
    }
}

// keval: r19 VERBATIM. Coalesced epsT float4, LDS float table (4KB),
// Catmull-Rom cubic. No fences, no atomics — plain partial store.
__global__ __launch_bounds__(256) void keval(const float* __restrict__ epsT,
                                             const float2* __restrict__ msdT,
                                             const float* __restrict__ table,
                                             float* __restrict__ partial)
{
    const int bid = blockIdx.x;
    const int ck  = bid >> 3;
    const int q   = bid & 7;
    const int j0  = q << 10;
    const int t   = threadIdx.x;

    const float4 e4 = *(const float4*)(epsT + ((size_t)ck << 13) + j0 + (t << 2));
    const float e[4] = {e4.x, e4.y, e4.z, e4.w};

    __shared__ float2 rowp[32];
    if (t < 32) rowp[t] = msdT[(ck << 8) + (q << 5) + t];

    __shared__ float tab[TN];                      // 4KB
    const float* __restrict__ gt = table + (ck << 10);
#pragma unroll
    for (int p = 0; p < 4; ++p)
        tab[t + (p << 8)] = gt[t + (p << 8)];
    __syncthreads();

    const float2 ms = rowp[t >> 3];                // 4 samples share one row
    float r = 0.f;
#pragma unroll
    for (int u = 0; u < 4; ++u) {
        const float z  = fmaf(e[u], ms.y, ms.x);
        const float zc = fminf(fmaxf(z, -ZCLAMP), ZCLAMP);
        const float x  = fmaf(zc, INVH, 512.0f);   // (zc-ZMIN)*INVH
        const float fg = floorf(x);
        const float f  = x - fg;
        const int  ig  = (int)fg;                  // in [3,1020]
        const float Lm = tab[ig - 1];
        const float L0 = tab[ig];
        const float L1 = tab[ig + 1];
        const float L2 = tab[ig + 2];
        const float m0 = 0.5f * (L1 - Lm);
        const float m1 = 0.5f * (L2 - L0);
        const float dl = L1 - L0;
        const float c2 = 3.f * dl - 2.f * m0 - m1;
        const float c3 = m0 + m1 - 2.f * dl;
        const float L  = fmaf(f, fmaf(f, fmaf(f, c3, c2), m0), L0);
        r += fmaf(LN2, L, 0.5f * z * z);
    }

    for (int off = 32; off > 0; off >>= 1) r += __shfl_down(r, off, 64);
    __shared__ float wsum[4];
    if ((t & 63) == 0) wsum[t >> 6] = r;
    __syncthreads();
    if (t == 0) partial[bid] = (wsum[0] + wsum[1]) + (wsum[2] + wsum[3]);
}

// Separate 1-block finish (kernel boundary = coherence; no fences anywhere).
__global__ __launch_bounds__(256) void kfinal(const float* __restrict__ partial,
                                              float* __restrict__ out)
{
    const int t = threadIdx.x;
    double s = 0.0;
#pragma unroll
    for (int i = 0; i < NEV / 256; ++i) s += (double)partial[i * 256 + t];
    __shared__ double sd[256];
    sd[t] = s;
    __syncthreads();
    for (int off = 128; off > 0; off >>= 1) {
        if (t < off) sd[t] += sd[t + off];
        __syncthreads();
    }
    if (t == 0)
        out[0] = (float)(sd[0] * (1.0 / (double)(NC * M))
                         - (double)D * 5.545177444479562);   // - D*ln(256)
}

// ---- fallback (ws too small; not expected) ----
__global__ __launch_bounds__(256) void kfb(const float* __restrict__ eps,
                                           const float* __restrict__ mean,
                                           const float* __restrict__ logvar,
                                           float* __restrict__ partial)
{
    const int bid = blockIdx.x;
    const int ck  = bid >> 3;
    const int q   = bid & 7;
    const int c   = ck >> 5;
    const int k   = ck & (D - 1);
    const int j0  = q << 10;
    const int t   = threadIdx.x;

    __shared__ float4 prm[AGG];
    {
        const int row  = (c << 8) + t;
        const float mu = mean[row * D + k];
        const float lv = logvar[row * D + k];
        const float ev = __builtin_amdgcn_exp2f(-lv * LOG2E);
        prm[t] = make_float4(-0.5f * LOG2E * ev, LOG2E * mu * ev,
                             -0.5f * LOG2E * fmaf(mu * mu, ev, lv),
                             __builtin_amdgcn_exp2f(0.5f * LOG2E * lv));
    }
    __syncthreads();

    float zv[4], acc[4];
#pragma unroll
    for (int u = 0; u < 4; ++u) {
        const int j    = j0 + t + (u << 8);
        const float4 p = prm[j >> 5];
        const float mu = -0.5f * p.y * __builtin_amdgcn_rcpf(p.x);
        zv[u]  = fmaf(eps[(size_t)((c << 13) + j) * D + k], p.w, mu);
        acc[u] = 0.f;
    }
#pragma unroll 4
    for (int i = 0; i < AGG; ++i) {
        const float4 p = prm[i];
#pragma unroll
        for (int u = 0; u < 4; ++u)
            acc[u] += __builtin_amdgcn_exp2f(fmaf(fmaf(p.x, zv[u], p.y), zv[u], p.z));
    }
    float r = 0.f;
#pragma unroll
    for (int u = 0; u < 4; ++u)
        r += LN2 * __builtin_amdgcn_logf(acc[u]) + 0.5f * zv[u] * zv[u];

    for (int off = 32; off > 0; off >>= 1) r += __shfl_down(r, off, 64);
    __shared__ float wsum[4];
    if ((t & 63) == 0) wsum[t >> 6] = r;
    __syncthreads();
    if (t == 0) partial[bid] = (wsum[0] + wsum[1]) + (wsum[2] + wsum[3]);
}

extern "C" void kernel_launch(void* const* d_in, const int* in_sizes, int n_in,
                              void* d_out, int out_size, void* d_ws, size_t ws_size,
                              hipStream_t stream)
{
    const float* mean   = (const float*)d_in[0];
    const float* logvar = (const float*)d_in[1];
    const float* eps    = (const float*)d_in[2];
    float* out = (float*)d_out;

    float*  partial = (float*)d_ws;
    float4* params  = (float4*)((char*)d_ws + WS_PARAMS);
    float2* msdT    = (float2*)((char*)d_ws + WS_MSDT);
    float*  table   = (float*)((char*)d_ws + WS_TABLE);
    float*  epsT    = (float*)((char*)d_ws + WS_EPST);

    if (ws_size >= (size_t)WS_NEED) {
        kprep<<<NC * 256, 256, 0, stream>>>(eps, mean, logvar, epsT, params, msdT);
        ktable<<<256, 1024, 0, stream>>>(params, table);
        keval<<<NEV, 256, 0, stream>>>(epsT, msdT, table, partial);
    } else {
        kfb<<<NEV, 256, 0, stream>>>(eps, mean, logvar, partial);
    }
    kfinal<<<1, 256, 0, stream>>>(partial, out);
}